// Round 2
// baseline (43.251 us; speedup 1.0000x reference)
//
#include <hip/hip_runtime.h>
#include <math.h>

// RKN cell: B=4096, LOD=64, LSD=128, H=64, NB=15, NE=436 (band +-3)
// out layout (floats): post_mean[4096*128], post_cu[4096*64], post_cl, post_cs,
//                      next_mean[4096*128], next_cu, next_cl, next_cs
#define O_PM   0
#define O_PCU  524288
#define O_PCL  786432
#define O_PCS  1048576
#define O_NM   1310720
#define O_NCU  1835008
#define O_NCL  2097152
#define O_NCS  2359296

__global__ __launch_bounds__(512, 4)
void rkn_kernel(const float* __restrict__ prior_mean,
                const float* __restrict__ cov_u,
                const float* __restrict__ cov_l,
                const float* __restrict__ cov_s,
                const float* __restrict__ obs,
                const float* __restrict__ obs_var,
                const float* __restrict__ W1,
                const float* __restrict__ b1,
                const float* __restrict__ W2,
                const float* __restrict__ b2,
                const float* __restrict__ W3,
                const float* __restrict__ b3,
                const float* __restrict__ tm11b,
                const float* __restrict__ tm12b,
                const float* __restrict__ tm21b,
                const float* __restrict__ tm22b,
                const float* __restrict__ ltn,
                float* __restrict__ out)
{
    // LDS layout (floats). Weights region is UNIONed with tm region
    // (phase-separated by barriers).
    //  W1q: [0,8320)    32 k4-rows * 65 float4 (k-packed, transposed, pad 65)
    //  W2q: [8320,12480) 16 * 65 float4
    //  W3q: [12480,13504) 16 k4 * 16 float4
    //  tmv: [0,13952)   [m][r][436]  (union)
    //  pm_s:[13952,14976) [8][128]; pcu/pcl/pcs: [8][64] each
    //  logit_s/coef_s: [8][16] each
    __shared__ __align__(16) float smem[16768];
    float4* W1q = (float4*)smem;
    float4* W2q = (float4*)(smem + 8320);
    float4* W3q = (float4*)(smem + 12480);
    float*  tmv = smem;
    float*  pm_s    = smem + 13952;
    float*  pcu_s   = smem + 14976;
    float*  pcl_s   = smem + 15488;
    float*  pcs_s   = smem + 16000;
    float*  logit_s = smem + 16512;
    float*  coef_s  = smem + 16640;

    const int tid  = threadIdx.x;
    const int wid  = tid >> 6;
    const int lane = tid & 63;
    const int row  = blockIdx.x * 8 + wid;

    // ---- stage weights: k-packed float4, transposed so lane j reads contig ----
    for (int idx = tid; idx < 2048; idx += 512) {
        int j = idx & 63, k4 = idx >> 6;
        W1q[k4 * 65 + j] = *(const float4*)(W1 + j * 128 + k4 * 4);
    }
    for (int idx = tid; idx < 1024; idx += 512) {
        int j = idx & 63, k4 = idx >> 6;
        W2q[k4 * 65 + j] = *(const float4*)(W2 + j * 64 + k4 * 4);
    }
    for (int idx = tid; idx < 256; idx += 512) {
        int j = idx & 15, k4 = idx >> 4;
        float4 v = make_float4(0.f, 0.f, 0.f, 0.f);
        if (j < 15) v = *(const float4*)(W3 + j * 64 + k4 * 4);
        W3q[k4 * 16 + j] = v;
    }

    // ---- phase 1: Kalman update (wave w <-> row w) ----
    const float cu   = cov_u[row * 64 + lane];
    const float cl   = cov_l[row * 64 + lane];
    const float cs   = cov_s[row * 64 + lane];
    const float ob   = obs[row * 64 + lane];
    const float ov   = obs_var[row * 64 + lane];
    const float pmu0 = prior_mean[row * 128 + lane];
    const float pml0 = prior_mean[row * 128 + 64 + lane];

    const float denom = cu + ov;
    const float qu  = cu / denom;
    const float ql  = cs / denom;
    const float res = ob - pmu0;
    const float pmu = pmu0 + qu * res;
    const float pml = pml0 + ql * res;
    const float cf  = 1.f - qu;
    const float pcu = cf * cu;
    const float pcl = cl - ql * cs;
    const float pcs = cf * cs;

    out[O_PM  + row * 128 + lane]      = pmu;
    out[O_PM  + row * 128 + 64 + lane] = pml;
    out[O_PCU + row * 64 + lane] = pcu;
    out[O_PCL + row * 64 + lane] = pcl;
    out[O_PCS + row * 64 + lane] = pcs;

    pm_s [wid * 128 + lane]      = pmu;
    pm_s [wid * 128 + 64 + lane] = pml;
    pcu_s[wid * 64 + lane] = pcu;
    pcl_s[wid * 64 + lane] = pcl;
    pcs_s[wid * 64 + lane] = pcs;

    __syncthreads();

    // ---- phase 2: MLP (activations in regs; k-broadcast via readlane) ----
    float acc = b1[lane];
#pragma unroll
    for (int k4 = 0; k4 < 32; ++k4) {
        float4 w = W1q[k4 * 65 + lane];
        float src = (k4 < 16) ? pmu : pml;
        acc += w.x * __shfl(src, (4 * k4 + 0) & 63, 64);
        acc += w.y * __shfl(src, (4 * k4 + 1) & 63, 64);
        acc += w.z * __shfl(src, (4 * k4 + 2) & 63, 64);
        acc += w.w * __shfl(src, (4 * k4 + 3) & 63, 64);
    }
    const float h1 = tanhf(acc);

    acc = b2[lane];
#pragma unroll
    for (int k4 = 0; k4 < 16; ++k4) {
        float4 w = W2q[k4 * 65 + lane];
        acc += w.x * __shfl(h1, 4 * k4 + 0, 64);
        acc += w.y * __shfl(h1, 4 * k4 + 1, 64);
        acc += w.z * __shfl(h1, 4 * k4 + 2, 64);
        acc += w.w * __shfl(h1, 4 * k4 + 3, 64);
    }
    const float h2 = tanhf(acc);

    const int jj = lane & 15;
    acc = (jj < 15) ? b3[jj] : 0.f;
#pragma unroll
    for (int k4 = 0; k4 < 16; ++k4) {
        float4 w = W3q[k4 * 16 + jj];
        acc += w.x * __shfl(h2, 4 * k4 + 0, 64);
        acc += w.y * __shfl(h2, 4 * k4 + 1, 64);
        acc += w.z * __shfl(h2, 4 * k4 + 2, 64);
        acc += w.w * __shfl(h2, 4 * k4 + 3, 64);
    }
    if (lane < 15) logit_s[wid * 16 + lane] = acc;

    __syncthreads();   // [A] logits visible; all weight reads done

    {
        float mx = -1e30f;
#pragma unroll
        for (int k = 0; k < 15; ++k) mx = fmaxf(mx, logit_s[wid * 16 + k]);
        float s = 0.f;
#pragma unroll
        for (int k = 0; k < 15; ++k) s += __expf(logit_s[wid * 16 + k] - mx);
        if (lane < 15)
            coef_s[wid * 16 + lane] = __expf(logit_s[wid * 16 + lane] - mx) / s;
    }

    __syncthreads();   // [B] coeffs visible; safe to overwrite weights region

    // ---- phase 3: tm[m][r][e] = sum_k coeff[r][k] * basis_m[k][e] ----
    {
        const float cv0 = coef_s[lane];        // (r,k) = lane (r=lane>>4,k=lane&15)
        const float cv1 = coef_s[64 + lane];
        const bool act = (tid < 436);
        const int  e   = act ? tid : 0;
        float acc3[4][8];
#pragma unroll
        for (int m = 0; m < 4; ++m)
#pragma unroll
            for (int r = 0; r < 8; ++r) acc3[m][r] = 0.f;
#pragma unroll
        for (int k = 0; k < 15; ++k) {
            const float vb11 = tm11b[k * 436 + e];
            const float vb12 = tm12b[k * 436 + e];
            const float vb21 = tm21b[k * 436 + e];
            const float vb22 = tm22b[k * 436 + e];
#pragma unroll
            for (int r = 0; r < 8; ++r) {
                const int ci = r * 16 + k;
                const float c = (ci < 64) ? __shfl(cv0, ci, 64)
                                          : __shfl(cv1, ci - 64, 64);
                acc3[0][r] += c * vb11;
                acc3[1][r] += c * vb12;
                acc3[2][r] += c * vb21;
                acc3[3][r] += c * vb22;
            }
        }
        if (act) {
#pragma unroll
            for (int m = 0; m < 4; ++m)
#pragma unroll
                for (int r = 0; r < 8; ++r)
                    tmv[(m * 8 + r) * 436 + tid] = acc3[m][r];
        }
    }

    __syncthreads();   // [C] tm visible

    // ---- phase 4: banded mat-vec combos (lane i owns band row i) ----
    {
        const int i   = lane;
        const int jlo = (i - 3 > 0) ? (i - 3) : 0;
        const int ne  = ((i + 3 < 63) ? (i + 3) : 63) - jlo + 1;
        // CSR base: rows 0-3 ramp up (4,5,6,7), rows 4-61 full 7-wide,
        // rows 62,63 truncated above (6,5,4 entries for 61,62,63).
        const int base = (i < 4)  ? (i * (i + 7)) / 2
                       : (i <= 61) ? (7 * i - 6)
                       : (i == 62) ? 427 : 432;

        float nmu = 0.f, nml = 0.f, ncu = 0.f, ncl = 0.f, ncs = 0.f;
#pragma unroll
        for (int d = 0; d < 7; ++d) {
            if (d < ne) {
                const int j  = jlo + d;
                const int eI = base + d;
                float t11 = tmv[(0 * 8 + wid) * 436 + eI];
                float t12 = tmv[(1 * 8 + wid) * 436 + eI];
                float t21 = tmv[(2 * 8 + wid) * 436 + eI];
                float t22 = tmv[(3 * 8 + wid) * 436 + eI];
                if (j == i) { t11 += 1.f; t22 += 1.f; }
                const float mu  = pm_s[wid * 128 + j];
                const float ml  = pm_s[wid * 128 + 64 + j];
                const float vcu = pcu_s[wid * 64 + j];
                const float vcl = pcl_s[wid * 64 + j];
                const float vcs = pcs_s[wid * 64 + j];
                nmu += t11 * mu + t12 * ml;
                nml += t21 * mu + t22 * ml;
                ncu += t11 * t11 * vcu + 2.f * t11 * t12 * vcs + t12 * t12 * vcl;
                ncl += t21 * t21 * vcu + 2.f * t21 * t22 * vcs + t22 * t22 * vcl;
                ncs += t21 * t11 * vcu + (t22 * t11 + t21 * t12) * vcs + t22 * t12 * vcl;
            }
        }
        const float xu = ltn[i];
        const float xl = ltn[64 + i];
        ncu += logf(expf(xu) + 1.f);   // softplus(trans noise), upper
        ncl += logf(expf(xl) + 1.f);   // lower

        out[O_NM  + row * 128 + i]      = nmu;
        out[O_NM  + row * 128 + 64 + i] = nml;
        out[O_NCU + row * 64 + i] = ncu;
        out[O_NCL + row * 64 + i] = ncl;
        out[O_NCS + row * 64 + i] = ncs;
    }
}

extern "C" void kernel_launch(void* const* d_in, const int* in_sizes, int n_in,
                              void* d_out, int out_size, void* d_ws, size_t ws_size,
                              hipStream_t stream) {
    rkn_kernel<<<dim3(512), dim3(512), 0, stream>>>(
        (const float*)d_in[0],  // prior_mean
        (const float*)d_in[1],  // cov_u
        (const float*)d_in[2],  // cov_l
        (const float*)d_in[3],  // cov_s
        (const float*)d_in[4],  // obs
        (const float*)d_in[5],  // obs_var
        (const float*)d_in[6],  // W1
        (const float*)d_in[7],  // b1
        (const float*)d_in[8],  // W2
        (const float*)d_in[9],  // b2
        (const float*)d_in[10], // W3
        (const float*)d_in[11], // b3
        (const float*)d_in[12], // tm11_basis
        (const float*)d_in[13], // tm12_basis
        (const float*)d_in[14], // tm21_basis
        (const float*)d_in[15], // tm22_basis
        (const float*)d_in[16], // log_trans_noise
        (float*)d_out);
}

// Round 3
// 27.624 us; speedup vs baseline: 1.5657x; 1.5657x over previous
//
#include <hip/hip_runtime.h>
#include <math.h>

// RKN cell: B=4096, LOD=64, LSD=128, H=64, NB=15, NE=436 (band +-3)
// out layout (floats): post_mean, post_cu, post_cl, post_cs,
//                      next_mean, next_cu, next_cl, next_cs
#define O_PM   0
#define O_PCU  524288
#define O_PCL  786432
#define O_PCS  1048576
#define O_NM   1310720
#define O_NCU  1835008
#define O_NCL  2097152
#define O_NCS  2359296

__device__ __forceinline__ float rlane(float v, int l) {
    return __uint_as_float(__builtin_amdgcn_readlane(__float_as_uint(v), l));
}
// pack two f32 -> one u32 holding two bf16 (RNE-ish), a in low half, b in high
__device__ __forceinline__ unsigned pk2(float a, float b) {
    unsigned ua = __float_as_uint(a), ub = __float_as_uint(b);
    ua += 0x7fffu + ((ua >> 16) & 1u);
    ub += 0x7fffu + ((ub >> 16) & 1u);
    return (ua >> 16) | (ub & 0xffff0000u);
}
__device__ __forceinline__ float lo16(unsigned w) { return __uint_as_float(w << 16); }
__device__ __forceinline__ float hi16(unsigned w) { return __uint_as_float(w & 0xffff0000u); }
__device__ __forceinline__ unsigned short tobf(float a) {
    unsigned ua = __float_as_uint(a);
    ua += 0x7fffu + ((ua >> 16) & 1u);
    return (unsigned short)(ua >> 16);
}
__device__ __forceinline__ float frombf(unsigned short u) {
    return __uint_as_float(((unsigned)u) << 16);
}
__device__ __forceinline__ float ftanh(float x) {
    float e = __expf(2.f * x);
    return 1.f - 2.f / (e + 1.f);
}

// LDS word map (4-byte words), total 8064 words = 32256 B -> 5 blocks/CU:
//  [0,4096)   W1v  [16 k8][64 j] uint4 (8 bf16 each)     } union with
//  [4096,6144) W2v [8 k8][64 j] uint4                    } tmv[16][436] bf16
//  [6144,6656) W3v [8 k8][16 j] uint4                    } (= 3488 words)
//  [6656,7168) pm_s  [4][128] f32
//  [7168,7424) pcu_s [4][64]
//  [7424,7680) pcl_s [4][64]
//  [7680,7936) pcs_s [4][64]
//  [7936,8000) logit_s [4][16]
//  [8000,8064) coef_s  [4][16]
__global__ __launch_bounds__(256, 5)
void rkn_kernel(const float* __restrict__ prior_mean,
                const float* __restrict__ cov_u,
                const float* __restrict__ cov_l,
                const float* __restrict__ cov_s,
                const float* __restrict__ obs,
                const float* __restrict__ obs_var,
                const float* __restrict__ W1,
                const float* __restrict__ b1,
                const float* __restrict__ W2,
                const float* __restrict__ b2,
                const float* __restrict__ W3,
                const float* __restrict__ b3,
                const float* __restrict__ tm11b,
                const float* __restrict__ tm12b,
                const float* __restrict__ tm21b,
                const float* __restrict__ tm22b,
                const float* __restrict__ ltn,
                float* __restrict__ out)
{
    __shared__ __align__(16) unsigned smem[8064];
    uint4* W1v = (uint4*)smem;
    uint4* W2v = (uint4*)(smem + 4096);
    uint4* W3v = (uint4*)(smem + 6144);
    unsigned short* tmv = (unsigned short*)smem;     // union with weights
    float* pm_s    = (float*)(smem + 6656);
    float* pcu_s   = (float*)(smem + 7168);
    float* pcl_s   = (float*)(smem + 7424);
    float* pcs_s   = (float*)(smem + 7680);
    float* logit_s = (float*)(smem + 7936);
    float* coef_s  = (float*)(smem + 8000);

    const int tid  = threadIdx.x;
    const int wid  = tid >> 6;
    const int lane = tid & 63;
    const int row  = blockIdx.x * 4 + wid;
    const int jj   = lane & 15;

    // ---- issue per-row global loads early (hide under staging) ----
    const float cu   = cov_u[row * 64 + lane];
    const float cl   = cov_l[row * 64 + lane];
    const float cs   = cov_s[row * 64 + lane];
    const float ob   = obs[row * 64 + lane];
    const float ov   = obs_var[row * 64 + lane];
    const float pmu0 = prior_mean[row * 128 + lane];
    const float pml0 = prior_mean[row * 128 + 64 + lane];
    const float bias1 = b1[lane];
    const float bias2 = b2[lane];
    const float bias3 = (jj < 15) ? b3[jj] : 0.f;

    // ---- stage weights as bf16 pairs (k-packed, j-transposed) ----
#pragma unroll
    for (int it = 0; it < 4; ++it) {
        const int idx = tid + it * 256;
        const int j = idx & 63, k8 = idx >> 6;
        const float4* p = (const float4*)(W1 + j * 128 + k8 * 8);
        const float4 a = p[0], b = p[1];
        W1v[idx] = make_uint4(pk2(a.x, a.y), pk2(a.z, a.w), pk2(b.x, b.y), pk2(b.z, b.w));
    }
#pragma unroll
    for (int it = 0; it < 2; ++it) {
        const int idx = tid + it * 256;
        const int j = idx & 63, k8 = idx >> 6;
        const float4* p = (const float4*)(W2 + j * 64 + k8 * 8);
        const float4 a = p[0], b = p[1];
        W2v[idx] = make_uint4(pk2(a.x, a.y), pk2(a.z, a.w), pk2(b.x, b.y), pk2(b.z, b.w));
    }
    if (tid < 128) {
        const int j = tid & 15, k8 = tid >> 4;
        uint4 v = make_uint4(0u, 0u, 0u, 0u);
        if (j < 15) {
            const float4* p = (const float4*)(W3 + j * 64 + k8 * 8);
            const float4 a = p[0], b = p[1];
            v = make_uint4(pk2(a.x, a.y), pk2(a.z, a.w), pk2(b.x, b.y), pk2(b.z, b.w));
        }
        W3v[k8 * 16 + j] = v;
    }

    // ---- phase 1: Kalman update ----
    const float denom = cu + ov;
    const float qu  = cu / denom;
    const float ql  = cs / denom;
    const float res = ob - pmu0;
    const float pmu = pmu0 + qu * res;
    const float pml = pml0 + ql * res;
    const float cf  = 1.f - qu;
    const float pcu = cf * cu;
    const float pcl = cl - ql * cs;
    const float pcs = cf * cs;

    out[O_PM  + row * 128 + lane]      = pmu;
    out[O_PM  + row * 128 + 64 + lane] = pml;
    out[O_PCU + row * 64 + lane] = pcu;
    out[O_PCL + row * 64 + lane] = pcl;
    out[O_PCS + row * 64 + lane] = pcs;

    pm_s [wid * 128 + lane]      = pmu;
    pm_s [wid * 128 + 64 + lane] = pml;
    pcu_s[wid * 64 + lane] = pcu;
    pcl_s[wid * 64 + lane] = pcl;
    pcs_s[wid * 64 + lane] = pcs;

    __syncthreads();

    // ---- phase 2: MLP; weights bf16x8 per 16B LDS read, readlane broadcast ----
    float ac0 = bias1, ac1 = 0.f, ac2 = 0.f, ac3 = 0.f;
#pragma unroll
    for (int k8 = 0; k8 < 16; ++k8) {
        const uint4 wv = W1v[k8 * 64 + lane];
        const float src = (k8 < 8) ? pmu : pml;
        const int bl = (k8 & 7) * 8;
        ac0 += lo16(wv.x) * rlane(src, bl + 0);
        ac1 += hi16(wv.x) * rlane(src, bl + 1);
        ac2 += lo16(wv.y) * rlane(src, bl + 2);
        ac3 += hi16(wv.y) * rlane(src, bl + 3);
        ac0 += lo16(wv.z) * rlane(src, bl + 4);
        ac1 += hi16(wv.z) * rlane(src, bl + 5);
        ac2 += lo16(wv.w) * rlane(src, bl + 6);
        ac3 += hi16(wv.w) * rlane(src, bl + 7);
    }
    const float h1v = ftanh((ac0 + ac1) + (ac2 + ac3));

    ac0 = bias2; ac1 = 0.f; ac2 = 0.f; ac3 = 0.f;
#pragma unroll
    for (int k8 = 0; k8 < 8; ++k8) {
        const uint4 wv = W2v[k8 * 64 + lane];
        const int bl = k8 * 8;
        ac0 += lo16(wv.x) * rlane(h1v, bl + 0);
        ac1 += hi16(wv.x) * rlane(h1v, bl + 1);
        ac2 += lo16(wv.y) * rlane(h1v, bl + 2);
        ac3 += hi16(wv.y) * rlane(h1v, bl + 3);
        ac0 += lo16(wv.z) * rlane(h1v, bl + 4);
        ac1 += hi16(wv.z) * rlane(h1v, bl + 5);
        ac2 += lo16(wv.w) * rlane(h1v, bl + 6);
        ac3 += hi16(wv.w) * rlane(h1v, bl + 7);
    }
    const float h2v = ftanh((ac0 + ac1) + (ac2 + ac3));

    ac0 = bias3; ac1 = 0.f; ac2 = 0.f; ac3 = 0.f;
#pragma unroll
    for (int k8 = 0; k8 < 8; ++k8) {
        const uint4 wv = W3v[k8 * 16 + jj];
        const int bl = k8 * 8;
        ac0 += lo16(wv.x) * rlane(h2v, bl + 0);
        ac1 += hi16(wv.x) * rlane(h2v, bl + 1);
        ac2 += lo16(wv.y) * rlane(h2v, bl + 2);
        ac3 += hi16(wv.y) * rlane(h2v, bl + 3);
        ac0 += lo16(wv.z) * rlane(h2v, bl + 4);
        ac1 += hi16(wv.z) * rlane(h2v, bl + 5);
        ac2 += lo16(wv.w) * rlane(h2v, bl + 6);
        ac3 += hi16(wv.w) * rlane(h2v, bl + 7);
    }
    if (lane < 15) logit_s[wid * 16 + lane] = (ac0 + ac1) + (ac2 + ac3);

    __syncthreads();   // logits visible; all weight LDS reads done? (NO - W reads done above, tm overwrite comes after next barrier)

    {
        float mx = -1e30f;
#pragma unroll
        for (int k = 0; k < 15; ++k) mx = fmaxf(mx, logit_s[wid * 16 + k]);
        float s = 0.f;
#pragma unroll
        for (int k = 0; k < 15; ++k) s += __expf(logit_s[wid * 16 + k] - mx);
        if (lane < 15)
            coef_s[wid * 16 + lane] = __expf(logit_s[wid * 16 + lane] - mx) / s;
    }

    __syncthreads();   // coeffs visible; safe to overwrite weights with tmv

    // ---- phase 3: tm[m][r][e] = sum_k coeff[r][k]*basis_m[k][e], bf16 out ----
    {
        const float cvv = coef_s[lane];       // flat [r*16+k], k<15 used
        const int  e0 = tid, e1 = tid + 256;
        const bool act1 = (e1 < 436);
        float a3[2][4][4];
#pragma unroll
        for (int ee = 0; ee < 2; ++ee)
#pragma unroll
            for (int m = 0; m < 4; ++m)
#pragma unroll
                for (int r = 0; r < 4; ++r) a3[ee][m][r] = 0.f;

#pragma unroll 3
        for (int k = 0; k < 15; ++k) {
            const float c0 = rlane(cvv, k);
            const float c1 = rlane(cvv, 16 + k);
            const float c2 = rlane(cvv, 32 + k);
            const float c3 = rlane(cvv, 48 + k);
            const float v00 = tm11b[k * 436 + e0];
            const float v10 = tm12b[k * 436 + e0];
            const float v20 = tm21b[k * 436 + e0];
            const float v30 = tm22b[k * 436 + e0];
            a3[0][0][0] += c0 * v00; a3[0][0][1] += c1 * v00; a3[0][0][2] += c2 * v00; a3[0][0][3] += c3 * v00;
            a3[0][1][0] += c0 * v10; a3[0][1][1] += c1 * v10; a3[0][1][2] += c2 * v10; a3[0][1][3] += c3 * v10;
            a3[0][2][0] += c0 * v20; a3[0][2][1] += c1 * v20; a3[0][2][2] += c2 * v20; a3[0][2][3] += c3 * v20;
            a3[0][3][0] += c0 * v30; a3[0][3][1] += c1 * v30; a3[0][3][2] += c2 * v30; a3[0][3][3] += c3 * v30;
            if (act1) {
                const float v01 = tm11b[k * 436 + e1];
                const float v11 = tm12b[k * 436 + e1];
                const float v21 = tm21b[k * 436 + e1];
                const float v31 = tm22b[k * 436 + e1];
                a3[1][0][0] += c0 * v01; a3[1][0][1] += c1 * v01; a3[1][0][2] += c2 * v01; a3[1][0][3] += c3 * v01;
                a3[1][1][0] += c0 * v11; a3[1][1][1] += c1 * v11; a3[1][1][2] += c2 * v11; a3[1][1][3] += c3 * v11;
                a3[1][2][0] += c0 * v21; a3[1][2][1] += c1 * v21; a3[1][2][2] += c2 * v21; a3[1][2][3] += c3 * v21;
                a3[1][3][0] += c0 * v31; a3[1][3][1] += c1 * v31; a3[1][3][2] += c2 * v31; a3[1][3][3] += c3 * v31;
            }
        }
#pragma unroll
        for (int m = 0; m < 4; ++m)
#pragma unroll
            for (int r = 0; r < 4; ++r) {
                tmv[(m * 4 + r) * 436 + e0] = tobf(a3[0][m][r]);
                if (act1) tmv[(m * 4 + r) * 436 + e1] = tobf(a3[1][m][r]);
            }
    }

    __syncthreads();   // tm visible

    // ---- phase 4: banded mat-vec combos (lane i owns band row i) ----
    {
        const int i   = lane;
        const int jlo = (i - 3 > 0) ? (i - 3) : 0;
        const int ne  = ((i + 3 < 63) ? (i + 3) : 63) - jlo + 1;
        const int base = (i < 4)  ? (i * (i + 7)) / 2
                       : (i <= 61) ? (7 * i - 6)
                       : (i == 62) ? 427 : 432;

        float nmu = 0.f, nml = 0.f, ncu = 0.f, ncl = 0.f, ncs = 0.f;
#pragma unroll
        for (int d = 0; d < 7; ++d) {
            if (d < ne) {
                const int j  = jlo + d;
                const int eI = base + d;
                float t11 = frombf(tmv[(0 * 4 + wid) * 436 + eI]);
                float t12 = frombf(tmv[(1 * 4 + wid) * 436 + eI]);
                float t21 = frombf(tmv[(2 * 4 + wid) * 436 + eI]);
                float t22 = frombf(tmv[(3 * 4 + wid) * 436 + eI]);
                if (j == i) { t11 += 1.f; t22 += 1.f; }
                const float mu  = pm_s[wid * 128 + j];
                const float ml  = pm_s[wid * 128 + 64 + j];
                const float vcu = pcu_s[wid * 64 + j];
                const float vcl = pcl_s[wid * 64 + j];
                const float vcs = pcs_s[wid * 64 + j];
                nmu += t11 * mu + t12 * ml;
                nml += t21 * mu + t22 * ml;
                ncu += t11 * t11 * vcu + 2.f * t11 * t12 * vcs + t12 * t12 * vcl;
                ncl += t21 * t21 * vcu + 2.f * t21 * t22 * vcs + t22 * t22 * vcl;
                ncs += t21 * t11 * vcu + (t22 * t11 + t21 * t12) * vcs + t22 * t12 * vcl;
            }
        }
        const float xu = ltn[i];
        const float xl = ltn[64 + i];
        ncu += logf(expf(xu) + 1.f);
        ncl += logf(expf(xl) + 1.f);

        out[O_NM  + row * 128 + i]      = nmu;
        out[O_NM  + row * 128 + 64 + i] = nml;
        out[O_NCU + row * 64 + i] = ncu;
        out[O_NCL + row * 64 + i] = ncl;
        out[O_NCS + row * 64 + i] = ncs;
    }
}

extern "C" void kernel_launch(void* const* d_in, const int* in_sizes, int n_in,
                              void* d_out, int out_size, void* d_ws, size_t ws_size,
                              hipStream_t stream) {
    rkn_kernel<<<dim3(1024), dim3(256), 0, stream>>>(
        (const float*)d_in[0],  // prior_mean
        (const float*)d_in[1],  // cov_u
        (const float*)d_in[2],  // cov_l
        (const float*)d_in[3],  // cov_s
        (const float*)d_in[4],  // obs
        (const float*)d_in[5],  // obs_var
        (const float*)d_in[6],  // W1
        (const float*)d_in[7],  // b1
        (const float*)d_in[8],  // W2
        (const float*)d_in[9],  // b2
        (const float*)d_in[10], // W3
        (const float*)d_in[11], // b3
        (const float*)d_in[12], // tm11_basis
        (const float*)d_in[13], // tm12_basis
        (const float*)d_in[14], // tm21_basis
        (const float*)d_in[15], // tm22_basis
        (const float*)d_in[16], // log_trans_noise
        (float*)d_out);
}